// Round 1
// baseline (375.077 us; speedup 1.0000x reference)
//
#include <hip/hip_runtime.h>

#define BATCH 4
#define NH    16
#define HD    64
#define SQ    2048
#define SKV   2048
#define DM    1024

typedef __attribute__((ext_vector_type(8))) __bf16 bf16x8;
typedef __attribute__((ext_vector_type(4))) __bf16 bf16x4;
typedef __attribute__((ext_vector_type(4))) float  f32x4;

static __device__ __forceinline__ bf16x4 cvt4(float4 v) {
    bf16x4 r;
    r[0] = (__bf16)v.x; r[1] = (__bf16)v.y; r[2] = (__bf16)v.z; r[3] = (__bf16)v.w;
    return r;
}

// ---------------------------------------------------------------------------
// K0: convert W (fp32 DxD) to bf16
// ---------------------------------------------------------------------------
__global__ void kconv_w(const float* __restrict__ W, __bf16* __restrict__ Wb) {
    int i = blockIdx.x * 256 + threadIdx.x;        // 262144 float4s
    float4 v = *(const float4*)(W + (size_t)i * 4);
    *(bf16x4*)(Wb + (size_t)i * 4) = cvt4(v);
}

// ---------------------------------------------------------------------------
// K1: Z[bh, k] = sum_q exp(QK^T / 32)
// grid (8 kblocks, 64 bh); block 256; k-block = 256 cols (64 per wave)
// ---------------------------------------------------------------------------
__global__ __launch_bounds__(256, 2) void kz(const float* __restrict__ q,
                                             const float* __restrict__ k,
                                             float* __restrict__ Z) {
    const int kb = blockIdx.x;
    const int bh = blockIdx.y;
    const int b = bh >> 4, h = bh & 15;
    const int t = threadIdx.x;
    const int w = t >> 6, lane = t & 63;
    const int lo16 = lane & 15, quad = lane >> 4;

    __shared__ __bf16 Ks[256 * 72];
    __shared__ __bf16 Qs[64 * 72];

    const float* kbase = k + (size_t)(b * SKV + kb * 256) * DM + h * HD;
    const float* qbase = q + (size_t)(b * SQ) * DM + h * HD;

    // stage K block 256x64 (resident for whole kernel)
#pragma unroll
    for (int i = 0; i < 16; ++i) {
        int idx = t + i * 256;
        int row = idx >> 4, c4 = idx & 15;
        float4 v = *(const float4*)(kbase + (size_t)row * DM + c4 * 4);
        *(bf16x4*)(&Ks[row * 72 + c4 * 4]) = cvt4(v);
    }

    float zacc[4] = {0.f, 0.f, 0.f, 0.f};

    for (int qt = 0; qt < 32; ++qt) {
        __syncthreads();
#pragma unroll
        for (int i = 0; i < 4; ++i) {
            int idx = t + i * 256;
            int row = idx >> 4, c4 = idx & 15;
            float4 v = *(const float4*)(qbase + (size_t)(qt * 64 + row) * DM + c4 * 4);
            *(bf16x4*)(&Qs[row * 72 + c4 * 4]) = cvt4(v);
        }
        __syncthreads();

        bf16x8 bk[4][2];
#pragma unroll
        for (int nt = 0; nt < 4; ++nt)
#pragma unroll
            for (int ks = 0; ks < 2; ++ks)
                bk[nt][ks] = *(const bf16x8*)(&Ks[(w * 64 + nt * 16 + lo16) * 72 + ks * 32 + quad * 8]);

#pragma unroll
        for (int mt = 0; mt < 4; ++mt) {
            bf16x8 aq0 = *(const bf16x8*)(&Qs[(mt * 16 + lo16) * 72 + quad * 8]);
            bf16x8 aq1 = *(const bf16x8*)(&Qs[(mt * 16 + lo16) * 72 + 32 + quad * 8]);
#pragma unroll
            for (int nt = 0; nt < 4; ++nt) {
                f32x4 acc = {0.f, 0.f, 0.f, 0.f};
                acc = __builtin_amdgcn_mfma_f32_16x16x32_bf16(aq0, bk[nt][0], acc, 0, 0, 0);
                acc = __builtin_amdgcn_mfma_f32_16x16x32_bf16(aq1, bk[nt][1], acc, 0, 0, 0);
                zacc[nt] += __expf(acc[0] * 0.03125f) + __expf(acc[1] * 0.03125f)
                          + __expf(acc[2] * 0.03125f) + __expf(acc[3] * 0.03125f);
            }
        }
    }

#pragma unroll
    for (int nt = 0; nt < 4; ++nt) {
        float v = zacc[nt];
        v += __shfl_xor(v, 16, 64);
        v += __shfl_xor(v, 32, 64);
        if (lane < 16)
            Z[(size_t)bh * SKV + kb * 256 + w * 64 + nt * 16 + lane] = v;
    }
}

// ---------------------------------------------------------------------------
// K2: O[q, :] = sum_k exp(S[q,k]) * V[k,:] / Z[k]   (per b,h) -> bf16
// grid (16 qblocks, 64 bh); block 256; q-block 128 (32 rows per wave)
// ---------------------------------------------------------------------------
__global__ __launch_bounds__(256, 2) void kattn(const float* __restrict__ q,
                                                const float* __restrict__ k,
                                                const float* __restrict__ v,
                                                const float* __restrict__ Z,
                                                __bf16* __restrict__ O) {
    const int qb = blockIdx.x;
    const int bh = blockIdx.y;
    const int b = bh >> 4, h = bh & 15;
    const int t = threadIdx.x;
    const int w = t >> 6, lane = t & 63;
    const int lo16 = lane & 15, quad = lane >> 4;

    __shared__ __bf16 Qs[128 * 72];
    __shared__ __bf16 Ks[64 * 72];
    __shared__ __bf16 Vt[64 * 72];          // transposed: [d][k], pre-scaled 1/Z
    __shared__ __bf16 Es[4 * 32 * 72];      // wave-private E strips

    const float* qbase = q + (size_t)(b * SQ + qb * 128) * DM + h * HD;
    const float* kbase = k + (size_t)(b * SKV) * DM + h * HD;
    const float* vbase = v + (size_t)(b * SKV) * DM + h * HD;
    const float* zbase = Z + (size_t)bh * SKV;

    // stage Q block 128x64
#pragma unroll
    for (int i = 0; i < 8; ++i) {
        int idx = t + i * 256;
        int row = idx >> 4, c4 = idx & 15;
        float4 vv = *(const float4*)(qbase + (size_t)row * DM + c4 * 4);
        *(bf16x4*)(&Qs[row * 72 + c4 * 4]) = cvt4(vv);
    }
    __syncthreads();

    // preload Q fragments (persist across k loop)
    bf16x8 aq[2][2];
#pragma unroll
    for (int mt = 0; mt < 2; ++mt)
#pragma unroll
        for (int ks = 0; ks < 2; ++ks)
            aq[mt][ks] = *(const bf16x8*)(&Qs[(w * 32 + mt * 16 + lo16) * 72 + ks * 32 + quad * 8]);

    f32x4 oacc[2][4];
    f32x4 zero = {0.f, 0.f, 0.f, 0.f};
#pragma unroll
    for (int mt = 0; mt < 2; ++mt)
#pragma unroll
        for (int nt = 0; nt < 4; ++nt)
            oacc[mt][nt] = zero;

    __bf16* Ew = &Es[w * 32 * 72];

    for (int kt = 0; kt < 32; ++kt) {
        __syncthreads();
        // stage K tile 64x64 (coalesced)
#pragma unroll
        for (int i = 0; i < 4; ++i) {
            int idx = t + i * 256;
            int row = idx >> 4, c4 = idx & 15;
            float4 vv = *(const float4*)(kbase + (size_t)(kt * 64 + row) * DM + c4 * 4);
            *(bf16x4*)(&Ks[row * 72 + c4 * 4]) = cvt4(vv);
        }
        // stage V tile transposed with 1/Z scaling (lane = key row -> conflict-free LDS writes)
        {
            int kk = lane;
            float rz = 1.0f / zbase[kt * 64 + kk];
#pragma unroll
            for (int i2 = 0; i2 < 4; ++i2) {
                int d0 = w * 4 + i2 * 16;
                float4 vv = *(const float4*)(vbase + (size_t)(kt * 64 + kk) * DM + d0);
                Vt[(d0 + 0) * 72 + kk] = (__bf16)(vv.x * rz);
                Vt[(d0 + 1) * 72 + kk] = (__bf16)(vv.y * rz);
                Vt[(d0 + 2) * 72 + kk] = (__bf16)(vv.z * rz);
                Vt[(d0 + 3) * 72 + kk] = (__bf16)(vv.w * rz);
            }
        }
        __syncthreads();

        bf16x8 bk[4][2];
#pragma unroll
        for (int nt = 0; nt < 4; ++nt)
#pragma unroll
            for (int ks = 0; ks < 2; ++ks)
                bk[nt][ks] = *(const bf16x8*)(&Ks[(nt * 16 + lo16) * 72 + ks * 32 + quad * 8]);

        // S = Q K^T / 32, E = exp(S), write wave-private E strip
#pragma unroll
        for (int mt = 0; mt < 2; ++mt) {
#pragma unroll
            for (int nt = 0; nt < 4; ++nt) {
                f32x4 s = zero;
                s = __builtin_amdgcn_mfma_f32_16x16x32_bf16(aq[mt][0], bk[nt][0], s, 0, 0, 0);
                s = __builtin_amdgcn_mfma_f32_16x16x32_bf16(aq[mt][1], bk[nt][1], s, 0, 0, 0);
#pragma unroll
                for (int r = 0; r < 4; ++r) {
                    float e = __expf(s[r] * 0.03125f);
                    Ew[(mt * 16 + quad * 4 + r) * 72 + nt * 16 + lo16] = (__bf16)e;
                }
            }
        }

        // O += E @ V'   (intra-wave LDS round trip; no barrier needed)
#pragma unroll
        for (int kk2 = 0; kk2 < 2; ++kk2) {
            bf16x8 ae0 = *(const bf16x8*)(&Ew[(lo16) * 72 + kk2 * 32 + quad * 8]);
            bf16x8 ae1 = *(const bf16x8*)(&Ew[(16 + lo16) * 72 + kk2 * 32 + quad * 8]);
#pragma unroll
            for (int nt = 0; nt < 4; ++nt) {
                bf16x8 bv = *(const bf16x8*)(&Vt[(nt * 16 + lo16) * 72 + kk2 * 32 + quad * 8]);
                oacc[0][nt] = __builtin_amdgcn_mfma_f32_16x16x32_bf16(ae0, bv, oacc[0][nt], 0, 0, 0);
                oacc[1][nt] = __builtin_amdgcn_mfma_f32_16x16x32_bf16(ae1, bv, oacc[1][nt], 0, 0, 0);
            }
        }
    }

    // write O strip (bf16)
    size_t obase = (size_t)(b * SQ + qb * 128 + w * 32) * DM + h * HD;
#pragma unroll
    for (int mt = 0; mt < 2; ++mt)
#pragma unroll
        for (int nt = 0; nt < 4; ++nt)
#pragma unroll
            for (int r = 0; r < 4; ++r)
                O[obase + (size_t)(mt * 16 + quad * 4 + r) * DM + nt * 16 + lo16] =
                    (__bf16)oacc[mt][nt][r];
}

// ---------------------------------------------------------------------------
// K3: out[n, i] = sum_j A[n,j] * W[i,j] + b[i]   (NT GEMM, 128x128 tiles)
// grid (8 nblocks, 64 mblocks); block 256 (2x2 waves, 64x64 per wave)
// ---------------------------------------------------------------------------
__global__ __launch_bounds__(256, 2) void kproj(const __bf16* __restrict__ A,
                                                const __bf16* __restrict__ Wb,
                                                const float* __restrict__ bias,
                                                float* __restrict__ out) {
    const int nb = blockIdx.x;
    const int mb = blockIdx.y;
    const int t = threadIdx.x;
    const int w = t >> 6, lane = t & 63;
    const int lo16 = lane & 15, quad = lane >> 4;
    const int wm = w & 1, wn = w >> 1;

    __shared__ __bf16 As[128 * 72];
    __shared__ __bf16 Bs[128 * 72];

    f32x4 acc[4][4];
    f32x4 zero = {0.f, 0.f, 0.f, 0.f};
#pragma unroll
    for (int mt = 0; mt < 4; ++mt)
#pragma unroll
        for (int nt = 0; nt < 4; ++nt)
            acc[mt][nt] = zero;

    const __bf16* abase = A + (size_t)(mb * 128) * DM;
    const __bf16* wbase = Wb + (size_t)(nb * 128) * DM;

    for (int kt = 0; kt < 16; ++kt) {
        __syncthreads();
#pragma unroll
        for (int i = 0; i < 4; ++i) {
            int idx = t + i * 256;             // 1024 chunks of 8 bf16
            int row = idx >> 3, ch = idx & 7;
            *(bf16x8*)(&As[row * 72 + ch * 8]) =
                *(const bf16x8*)(abase + (size_t)row * DM + kt * 64 + ch * 8);
            *(bf16x8*)(&Bs[row * 72 + ch * 8]) =
                *(const bf16x8*)(wbase + (size_t)row * DM + kt * 64 + ch * 8);
        }
        __syncthreads();

#pragma unroll
        for (int ks = 0; ks < 2; ++ks) {
            bf16x8 av[4], bv[4];
#pragma unroll
            for (int mt = 0; mt < 4; ++mt)
                av[mt] = *(const bf16x8*)(&As[(wm * 64 + mt * 16 + lo16) * 72 + ks * 32 + quad * 8]);
#pragma unroll
            for (int nt = 0; nt < 4; ++nt)
                bv[nt] = *(const bf16x8*)(&Bs[(wn * 64 + nt * 16 + lo16) * 72 + ks * 32 + quad * 8]);
#pragma unroll
            for (int mt = 0; mt < 4; ++mt)
#pragma unroll
                for (int nt = 0; nt < 4; ++nt)
                    acc[mt][nt] = __builtin_amdgcn_mfma_f32_16x16x32_bf16(av[mt], bv[nt], acc[mt][nt], 0, 0, 0);
        }
    }

    const int col0 = nb * 128 + wn * 64;
    const int row0 = mb * 128 + wm * 64;
#pragma unroll
    for (int nt = 0; nt < 4; ++nt) {
        float bb = bias[col0 + nt * 16 + lo16];
#pragma unroll
        for (int mt = 0; mt < 4; ++mt)
#pragma unroll
            for (int r = 0; r < 4; ++r)
                out[(size_t)(row0 + mt * 16 + quad * 4 + r) * DM + col0 + nt * 16 + lo16] =
                    acc[mt][nt][r] + bb;
    }
}

// ---------------------------------------------------------------------------
extern "C" void kernel_launch(void* const* d_in, const int* in_sizes, int n_in,
                              void* d_out, int out_size, void* d_ws, size_t ws_size,
                              hipStream_t stream) {
    const float* q    = (const float*)d_in[0];
    const float* k    = (const float*)d_in[1];
    const float* v    = (const float*)d_in[2];
    const float* W    = (const float*)d_in[3];
    const float* bias = (const float*)d_in[4];
    float* out = (float*)d_out;

    char* ws = (char*)d_ws;
    float*  Z  = (float*)ws;                                    // 512 KB
    __bf16* Wb = (__bf16*)(ws + (512 << 10));                   // 2 MB
    __bf16* O  = (__bf16*)(ws + (512 << 10) + (2 << 20));       // 16 MB

    kconv_w<<<dim3(1024), 256, 0, stream>>>(W, Wb);
    kz     <<<dim3(8, 64), 256, 0, stream>>>(q, k, Z);
    kattn  <<<dim3(16, 64), 256, 0, stream>>>(q, k, v, Z, O);
    kproj  <<<dim3(8, 64), 256, 0, stream>>>(O, Wb, bias, out);
}

// Round 2
// 330.319 us; speedup vs baseline: 1.1355x; 1.1355x over previous
//
#include <hip/hip_runtime.h>

#define NH    16
#define HD    64
#define SQ    2048
#define SKV   2048
#define DM    1024

typedef __attribute__((ext_vector_type(8))) __bf16 bf16x8;
typedef __attribute__((ext_vector_type(4))) __bf16 bf16x4;
typedef __attribute__((ext_vector_type(4))) float  f32x4;

static __device__ __forceinline__ bf16x4 cvt4(float4 v) {
    bf16x4 r;
    r[0] = (__bf16)v.x; r[1] = (__bf16)v.y; r[2] = (__bf16)v.z; r[3] = (__bf16)v.w;
    return r;
}

// ---------------------------------------------------------------------------
// kprep: [b][s][h*64+d] fp32  ->  [bh][s][d] bf16 (head-major)
// ---------------------------------------------------------------------------
__global__ void kprep(const float* __restrict__ src, __bf16* __restrict__ dst) {
    size_t g = (size_t)blockIdx.x * 256 + threadIdx.x;
    size_t o = g * 8;                      // 8 bf16 per thread
    int c  = (int)(o & 63);                // d offset (8-aligned)
    int s  = (int)((o >> 6) & 2047);
    int bh = (int)(o >> 17);
    int b = bh >> 4, h = bh & 15;
    const float* p = src + ((size_t)(b * SQ + s)) * DM + h * HD + c;
    float4 v0 = *(const float4*)p;
    float4 v1 = *(const float4*)(p + 4);
    bf16x8 r;
    r[0] = (__bf16)v0.x; r[1] = (__bf16)v0.y; r[2] = (__bf16)v0.z; r[3] = (__bf16)v0.w;
    r[4] = (__bf16)v1.x; r[5] = (__bf16)v1.y; r[6] = (__bf16)v1.z; r[7] = (__bf16)v1.w;
    *(bf16x8*)(dst + o) = r;
}

// ---------------------------------------------------------------------------
// kconv_w: W fp32 -> bf16
// ---------------------------------------------------------------------------
__global__ void kconv_w(const float* __restrict__ W, __bf16* __restrict__ Wb) {
    int i = blockIdx.x * 256 + threadIdx.x;
    float4 v = *(const float4*)(W + (size_t)i * 4);
    *(bf16x4*)(Wb + (size_t)i * 4) = cvt4(v);
}

// ---------------------------------------------------------------------------
// kz: Z[k] = sum_q exp(QK^T/32); epilogue writes Vt[bh][d][k] = bf16(V/Z)
// grid (8 kblocks, 64 bh); block 256; K-block 256 cols (64 per wave, in regs)
// ---------------------------------------------------------------------------
__global__ __launch_bounds__(256, 3) void kz(const __bf16* __restrict__ Qh,
                                             const __bf16* __restrict__ Kh,
                                             const float* __restrict__ v,
                                             __bf16* __restrict__ Vt) {
    const int kb = blockIdx.x;
    const int bh = blockIdx.y;
    const int b = bh >> 4, h = bh & 15;
    const int t = threadIdx.x;
    const int w = t >> 6, lane = t & 63;
    const int lo16 = lane & 15, quad = lane >> 4;

    __shared__ __bf16 Ks[256 * 72];
    __shared__ __bf16 Qs[64 * 72];
    __shared__ float  Zs[256];

    const __bf16* kbase = Kh + ((size_t)bh * SKV + kb * 256) * HD;
    const __bf16* qbase = Qh + (size_t)bh * SQ * HD;

    // stage K block 256x64 (contiguous copy)
#pragma unroll
    for (int i = 0; i < 8; ++i) {
        int idx = t + i * 256;
        int row = idx >> 3, ch = idx & 7;
        *(bf16x8*)(&Ks[row * 72 + ch * 8]) = *(const bf16x8*)(kbase + (size_t)idx * 8);
    }
    __syncthreads();

    // hoist K fragments into registers (B-operand: n = k-col, kdim = d)
    bf16x8 bk[4][2];
#pragma unroll
    for (int nt = 0; nt < 4; ++nt)
#pragma unroll
        for (int dh = 0; dh < 2; ++dh)
            bk[nt][dh] = *(const bf16x8*)(&Ks[(w * 64 + nt * 16 + lo16) * 72 + dh * 32 + quad * 8]);

    float zacc[4] = {0.f, 0.f, 0.f, 0.f};

    for (int qt = 0; qt < 32; ++qt) {
        __syncthreads();
#pragma unroll
        for (int i = 0; i < 2; ++i) {
            int idx = t + i * 256;
            int row = idx >> 3, ch = idx & 7;
            *(bf16x8*)(&Qs[row * 72 + ch * 8]) =
                *(const bf16x8*)(qbase + (size_t)qt * 64 * HD + idx * 8);
        }
        __syncthreads();

#pragma unroll
        for (int mt = 0; mt < 4; ++mt) {
            bf16x8 aq0 = *(const bf16x8*)(&Qs[(mt * 16 + lo16) * 72 + quad * 8]);
            bf16x8 aq1 = *(const bf16x8*)(&Qs[(mt * 16 + lo16) * 72 + 32 + quad * 8]);
#pragma unroll
            for (int nt = 0; nt < 4; ++nt) {
                f32x4 acc = {0.f, 0.f, 0.f, 0.f};
                acc = __builtin_amdgcn_mfma_f32_16x16x32_bf16(aq0, bk[nt][0], acc, 0, 0, 0);
                acc = __builtin_amdgcn_mfma_f32_16x16x32_bf16(aq1, bk[nt][1], acc, 0, 0, 0);
                zacc[nt] += __expf(acc[0] * 0.03125f) + __expf(acc[1] * 0.03125f)
                          + __expf(acc[2] * 0.03125f) + __expf(acc[3] * 0.03125f);
            }
        }
    }

#pragma unroll
    for (int nt = 0; nt < 4; ++nt) {
        float s = zacc[nt];
        s += __shfl_xor(s, 16, 64);
        s += __shfl_xor(s, 32, 64);
        if (lane < 16) Zs[w * 64 + nt * 16 + lane] = s;
    }
    __syncthreads();

    // epilogue: Vt[bh][d][kb*256 + t] = bf16(V[k][d] / Z[k]); t <-> k-col
    {
        float rz = 1.0f / Zs[t];
        const float* vrow = v + ((size_t)(b * SKV) + kb * 256 + t) * DM + h * HD;
        size_t vtb = (size_t)bh * HD * SKV + kb * 256 + t;
#pragma unroll
        for (int dc = 0; dc < 4; ++dc) {
            float4 a0 = *(const float4*)(vrow + dc * 16 + 0);
            float4 a1 = *(const float4*)(vrow + dc * 16 + 4);
            float4 a2 = *(const float4*)(vrow + dc * 16 + 8);
            float4 a3 = *(const float4*)(vrow + dc * 16 + 12);
            float tmp[16] = {a0.x, a0.y, a0.z, a0.w, a1.x, a1.y, a1.z, a1.w,
                             a2.x, a2.y, a2.z, a2.w, a3.x, a3.y, a3.z, a3.w};
#pragma unroll
            for (int j = 0; j < 16; ++j)
                Vt[vtb + (size_t)(dc * 16 + j) * SKV] = (__bf16)(tmp[j] * rz);
        }
    }
}

// ---------------------------------------------------------------------------
// kattn: O[q,:] = sum_k exp(S[q,k]) * Vt[:,k]   (Vt pre-scaled by 1/Z)
// S^T formulation: S^T = MFMA(A=K, B=Q) -> lane holds 4 consecutive k at
// fixed q -> packed b64 E writes; PV reads E row-major b128.
// grid (8 qblocks, 64 bh); block 256; q-block 256 (64 per wave)
// ---------------------------------------------------------------------------
__global__ __launch_bounds__(256, 2) void kattn(const __bf16* __restrict__ Qh,
                                                const __bf16* __restrict__ Kh,
                                                const __bf16* __restrict__ Vt,
                                                __bf16* __restrict__ O) {
    const int qb = blockIdx.x;
    const int bh = blockIdx.y;
    const int b = bh >> 4, h = bh & 15;
    const int t = threadIdx.x;
    const int w = t >> 6, lane = t & 63;
    const int lo16 = lane & 15, quad = lane >> 4;

    __shared__ __bf16 Ks[64 * 72];
    __shared__ __bf16 Vts[64 * 72];
    __shared__ __bf16 QE[256 * 72];   // Q staging, then per-wave E strips

    // stage Q block 256x64
    const __bf16* qgbase = Qh + ((size_t)bh * SQ + qb * 256) * HD;
#pragma unroll
    for (int i = 0; i < 8; ++i) {
        int idx = t + i * 256;
        int row = idx >> 3, ch = idx & 7;
        *(bf16x8*)(&QE[row * 72 + ch * 8]) = *(const bf16x8*)(qgbase + (size_t)idx * 8);
    }
    __syncthreads();

    // Q fragments (B-operand: n = q, kdim = d), persist in registers
    bf16x8 qf[4][2];
#pragma unroll
    for (int qt = 0; qt < 4; ++qt)
#pragma unroll
        for (int dh = 0; dh < 2; ++dh)
            qf[qt][dh] = *(const bf16x8*)(&QE[(w * 64 + qt * 16 + lo16) * 72 + dh * 32 + quad * 8]);

    f32x4 oacc[4][4];
    f32x4 zero = {0.f, 0.f, 0.f, 0.f};
#pragma unroll
    for (int qt = 0; qt < 4; ++qt)
#pragma unroll
        for (int nt = 0; nt < 4; ++nt)
            oacc[qt][nt] = zero;

    __bf16* Ew = &QE[w * 64 * 72];
    const __bf16* kgbase = Kh + (size_t)bh * SKV * HD;
    const __bf16* vtgbase = Vt + (size_t)bh * HD * SKV;

    for (int kt = 0; kt < 32; ++kt) {
        __syncthreads();
        // stage K tile 64x64 (contiguous) and Vt tile 64d x 64k (row = d)
#pragma unroll
        for (int i = 0; i < 2; ++i) {
            int idx = t + i * 256;
            int row = idx >> 3, ch = idx & 7;
            *(bf16x8*)(&Ks[row * 72 + ch * 8]) =
                *(const bf16x8*)(kgbase + (size_t)kt * 64 * HD + idx * 8);
            *(bf16x8*)(&Vts[row * 72 + ch * 8]) =
                *(const bf16x8*)(vtgbase + (size_t)row * SKV + kt * 64 + ch * 8);
        }
        __syncthreads();

        // S^T = K Q^T / 32; E = exp; packed b64 writes into wave-private strip
#pragma unroll
        for (int ktile = 0; ktile < 4; ++ktile) {
            bf16x8 ak0 = *(const bf16x8*)(&Ks[(ktile * 16 + lo16) * 72 + quad * 8]);
            bf16x8 ak1 = *(const bf16x8*)(&Ks[(ktile * 16 + lo16) * 72 + 32 + quad * 8]);
#pragma unroll
            for (int qt = 0; qt < 4; ++qt) {
                f32x4 s = zero;
                s = __builtin_amdgcn_mfma_f32_16x16x32_bf16(ak0, qf[qt][0], s, 0, 0, 0);
                s = __builtin_amdgcn_mfma_f32_16x16x32_bf16(ak1, qf[qt][1], s, 0, 0, 0);
                bf16x4 e;
                e[0] = (__bf16)__expf(s[0] * 0.03125f);
                e[1] = (__bf16)__expf(s[1] * 0.03125f);
                e[2] = (__bf16)__expf(s[2] * 0.03125f);
                e[3] = (__bf16)__expf(s[3] * 0.03125f);
                *(bf16x4*)(&Ew[(qt * 16 + lo16) * 72 + ktile * 16 + quad * 4]) = e;
            }
        }

        // O += E @ Vt^T   (intra-wave LDS round trip, no barrier)
#pragma unroll
        for (int kk2 = 0; kk2 < 2; ++kk2) {
            bf16x8 ae[4];
#pragma unroll
            for (int qt = 0; qt < 4; ++qt)
                ae[qt] = *(const bf16x8*)(&Ew[(qt * 16 + lo16) * 72 + kk2 * 32 + quad * 8]);
#pragma unroll
            for (int nt = 0; nt < 4; ++nt) {
                bf16x8 bv = *(const bf16x8*)(&Vts[(nt * 16 + lo16) * 72 + kk2 * 32 + quad * 8]);
#pragma unroll
                for (int qt = 0; qt < 4; ++qt)
                    oacc[qt][nt] = __builtin_amdgcn_mfma_f32_16x16x32_bf16(ae[qt], bv, oacc[qt][nt], 0, 0, 0);
            }
        }
    }

    // epilogue: O rows = b*SQ + qb*256 + w*64 + qt*16 + quad*4 + r
    size_t obase = ((size_t)(b * SQ) + qb * 256 + w * 64) * DM + h * HD;
#pragma unroll
    for (int qt = 0; qt < 4; ++qt)
#pragma unroll
        for (int nt = 0; nt < 4; ++nt)
#pragma unroll
            for (int r = 0; r < 4; ++r)
                O[obase + (size_t)(qt * 16 + quad * 4 + r) * DM + nt * 16 + lo16] =
                    (__bf16)oacc[qt][nt][r];
}

// ---------------------------------------------------------------------------
// kproj: out[n, i] = sum_j A[n,j] * W[i,j] + b[i]   (NT GEMM, 128x128 tiles)
// ---------------------------------------------------------------------------
__global__ __launch_bounds__(256, 2) void kproj(const __bf16* __restrict__ A,
                                                const __bf16* __restrict__ Wb,
                                                const float* __restrict__ bias,
                                                float* __restrict__ out) {
    const int nb = blockIdx.x;
    const int mb = blockIdx.y;
    const int t = threadIdx.x;
    const int w = t >> 6, lane = t & 63;
    const int lo16 = lane & 15, quad = lane >> 4;
    const int wm = w & 1, wn = w >> 1;

    __shared__ __bf16 As[128 * 72];
    __shared__ __bf16 Bs[128 * 72];

    f32x4 acc[4][4];
    f32x4 zero = {0.f, 0.f, 0.f, 0.f};
#pragma unroll
    for (int mt = 0; mt < 4; ++mt)
#pragma unroll
        for (int nt = 0; nt < 4; ++nt)
            acc[mt][nt] = zero;

    const __bf16* abase = A + (size_t)(mb * 128) * DM;
    const __bf16* wbase = Wb + (size_t)(nb * 128) * DM;

    for (int kt = 0; kt < 16; ++kt) {
        __syncthreads();
#pragma unroll
        for (int i = 0; i < 4; ++i) {
            int idx = t + i * 256;
            int row = idx >> 3, ch = idx & 7;
            *(bf16x8*)(&As[row * 72 + ch * 8]) =
                *(const bf16x8*)(abase + (size_t)row * DM + kt * 64 + ch * 8);
            *(bf16x8*)(&Bs[row * 72 + ch * 8]) =
                *(const bf16x8*)(wbase + (size_t)row * DM + kt * 64 + ch * 8);
        }
        __syncthreads();

#pragma unroll
        for (int ks = 0; ks < 2; ++ks) {
            bf16x8 av[4], bv[4];
#pragma unroll
            for (int mt = 0; mt < 4; ++mt)
                av[mt] = *(const bf16x8*)(&As[(wm * 64 + mt * 16 + lo16) * 72 + ks * 32 + quad * 8]);
#pragma unroll
            for (int nt = 0; nt < 4; ++nt)
                bv[nt] = *(const bf16x8*)(&Bs[(wn * 64 + nt * 16 + lo16) * 72 + ks * 32 + quad * 8]);
#pragma unroll
            for (int mt = 0; mt < 4; ++mt)
#pragma unroll
                for (int nt = 0; nt < 4; ++nt)
                    acc[mt][nt] = __builtin_amdgcn_mfma_f32_16x16x32_bf16(av[mt], bv[nt], acc[mt][nt], 0, 0, 0);
        }
    }

    const int col0 = nb * 128 + wn * 64;
    const int row0 = mb * 128 + wm * 64;
#pragma unroll
    for (int nt = 0; nt < 4; ++nt) {
        float bb = bias[col0 + nt * 16 + lo16];
#pragma unroll
        for (int mt = 0; mt < 4; ++mt)
#pragma unroll
            for (int r = 0; r < 4; ++r)
                out[(size_t)(row0 + mt * 16 + quad * 4 + r) * DM + col0 + nt * 16 + lo16] =
                    acc[mt][nt][r] + bb;
    }
}

// ---------------------------------------------------------------------------
extern "C" void kernel_launch(void* const* d_in, const int* in_sizes, int n_in,
                              void* d_out, int out_size, void* d_ws, size_t ws_size,
                              hipStream_t stream) {
    const float* q    = (const float*)d_in[0];
    const float* k    = (const float*)d_in[1];
    const float* v    = (const float*)d_in[2];
    const float* W    = (const float*)d_in[3];
    const float* bias = (const float*)d_in[4];
    float* out = (float*)d_out;

    char* ws = (char*)d_ws;
    __bf16* Qh = (__bf16*)ws;                          // 16 MB
    __bf16* Kh = (__bf16*)(ws + (16u << 20));          // 16 MB
    __bf16* Vt = (__bf16*)(ws + (32u << 20));          // 16 MB
    __bf16* Wb = (__bf16*)(ws + (48u << 20));          // 2 MB
    __bf16* O  = (__bf16*)(ws + (50u << 20));          // 16 MB

    kprep  <<<dim3(4096), 256, 0, stream>>>(q, Qh);
    kprep  <<<dim3(4096), 256, 0, stream>>>(k, Kh);
    kconv_w<<<dim3(1024), 256, 0, stream>>>(W, Wb);
    kz     <<<dim3(8, 64), 256, 0, stream>>>(Qh, Kh, v, Vt);
    kattn  <<<dim3(8, 64), 256, 0, stream>>>(Qh, Kh, Vt, O);
    kproj  <<<dim3(8, 64), 256, 0, stream>>>(O, Wb, bias, out);
}

// Round 3
// 298.492 us; speedup vs baseline: 1.2566x; 1.1066x over previous
//
#include <hip/hip_runtime.h>

#define NH    16
#define HD    64
#define SQ    2048
#define SKV   2048
#define DM    1024

typedef __attribute__((ext_vector_type(8))) __bf16 bf16x8;
typedef __attribute__((ext_vector_type(4))) __bf16 bf16x4;
typedef __attribute__((ext_vector_type(4))) float  f32x4;

// async global->LDS, 16B per lane; LDS dest = wave-uniform base + lane*16
#define ASYNC16(gp, lp)                                                        \
    __builtin_amdgcn_global_load_lds(                                          \
        (const __attribute__((address_space(1))) void*)(gp),                   \
        (__attribute__((address_space(3))) void*)(lp), 16, 0, 0)

// exp(x/32) = exp2(x * log2(e)/32): single v_mul + v_exp_f32
#if __has_builtin(__builtin_amdgcn_exp2f)
#define EXPS(x) __builtin_amdgcn_exp2f((x) * 0.04508422f)
#else
#define EXPS(x) __expf((x) * 0.03125f)
#endif

// swizzled LDS tile: 64 elems/row, 8 chunks of 8 bf16; chunk' = chunk ^ (row&7)
static __device__ __forceinline__ int swz(int row, int chunk) {
    return (row << 6) + (((chunk) ^ (row & 7)) << 3);
}

static __device__ __forceinline__ bf16x4 cvt4(float4 v) {
    bf16x4 r;
    r[0] = (__bf16)v.x; r[1] = (__bf16)v.y; r[2] = (__bf16)v.z; r[3] = (__bf16)v.w;
    return r;
}

// ---------------------------------------------------------------------------
// kprep: [b][s][h*64+d] fp32  ->  [bh][s][d] bf16 (head-major)
// ---------------------------------------------------------------------------
__global__ void kprep(const float* __restrict__ src, __bf16* __restrict__ dst) {
    size_t g = (size_t)blockIdx.x * 256 + threadIdx.x;
    size_t o = g * 8;
    int c  = (int)(o & 63);
    int s  = (int)((o >> 6) & 2047);
    int bh = (int)(o >> 17);
    int b = bh >> 4, h = bh & 15;
    const float* p = src + ((size_t)(b * SQ + s)) * DM + h * HD + c;
    float4 v0 = *(const float4*)p;
    float4 v1 = *(const float4*)(p + 4);
    bf16x8 r;
    r[0] = (__bf16)v0.x; r[1] = (__bf16)v0.y; r[2] = (__bf16)v0.z; r[3] = (__bf16)v0.w;
    r[4] = (__bf16)v1.x; r[5] = (__bf16)v1.y; r[6] = (__bf16)v1.z; r[7] = (__bf16)v1.w;
    *(bf16x8*)(dst + o) = r;
}

// ---------------------------------------------------------------------------
// kconv_w: W fp32 -> bf16
// ---------------------------------------------------------------------------
__global__ void kconv_w(const float* __restrict__ W, __bf16* __restrict__ Wb) {
    int i = blockIdx.x * 256 + threadIdx.x;
    float4 v = *(const float4*)(W + (size_t)i * 4);
    *(bf16x4*)(Wb + (size_t)i * 4) = cvt4(v);
}

// ---------------------------------------------------------------------------
// kz: Z[k] = sum_q exp(QK^T/32); epilogue writes Vt[bh][d][k] = bf16(V/Z)
// grid (64 bh, 8 kb): id = kb*64+bh -> bh pinned to XCD (L2 reuse of Q)
// ---------------------------------------------------------------------------
__global__ __launch_bounds__(256, 3) void kz(const __bf16* __restrict__ Qh,
                                             const __bf16* __restrict__ Kh,
                                             const float* __restrict__ v,
                                             __bf16* __restrict__ Vt) {
    const int bh = blockIdx.x;
    const int kb = blockIdx.y;
    const int b = bh >> 4, h = bh & 15;
    const int t = threadIdx.x;
    const int w = t >> 6, lane = t & 63;
    const int lo16 = lane & 15, quad = lane >> 4;
    const int wub = (t & 192) << 3;          // wave-uniform chunk base *8 elems

    __shared__ __bf16 Ks[256 * 64];
    __shared__ __bf16 Qs[64 * 64];
    __shared__ float  Zs[256];

    const __bf16* kbase = Kh + ((size_t)bh * SKV + kb * 256) * HD;
    const __bf16* qbase = Qh + (size_t)bh * SQ * HD;

    // async stage K 256x64 (swizzle folded into global offsets)
#pragma unroll
    for (int i = 0; i < 8; ++i) {
        int ci = i * 256 + t;
        int row = ci >> 3;
        int c = (ci & 7) ^ (row & 7);
        ASYNC16(kbase + row * 64 + c * 8, &Ks[i * 2048 + wub]);
    }
    __syncthreads();

    // hoist K fragments (B-operand: n = k-col, kdim = d)
    bf16x8 bk[4][2];
#pragma unroll
    for (int nt = 0; nt < 4; ++nt)
#pragma unroll
        for (int dh = 0; dh < 2; ++dh)
            bk[nt][dh] = *(const bf16x8*)(&Ks[swz(w * 64 + nt * 16 + lo16, dh * 4 + quad)]);

    float zacc[4] = {0.f, 0.f, 0.f, 0.f};

    for (int qt = 0; qt < 32; ++qt) {
        __syncthreads();
#pragma unroll
        for (int i = 0; i < 2; ++i) {
            int ci = i * 256 + t;
            int row = ci >> 3;
            int c = (ci & 7) ^ (row & 7);
            ASYNC16(qbase + (size_t)qt * 64 * HD + row * 64 + c * 8, &Qs[i * 2048 + wub]);
        }
        __syncthreads();

#pragma unroll
        for (int mt = 0; mt < 4; ++mt) {
            bf16x8 aq0 = *(const bf16x8*)(&Qs[swz(mt * 16 + lo16, quad)]);
            bf16x8 aq1 = *(const bf16x8*)(&Qs[swz(mt * 16 + lo16, 4 + quad)]);
#pragma unroll
            for (int nt = 0; nt < 4; ++nt) {
                f32x4 acc = {0.f, 0.f, 0.f, 0.f};
                acc = __builtin_amdgcn_mfma_f32_16x16x32_bf16(aq0, bk[nt][0], acc, 0, 0, 0);
                acc = __builtin_amdgcn_mfma_f32_16x16x32_bf16(aq1, bk[nt][1], acc, 0, 0, 0);
                zacc[nt] += EXPS(acc[0]) + EXPS(acc[1]) + EXPS(acc[2]) + EXPS(acc[3]);
            }
        }
    }

#pragma unroll
    for (int nt = 0; nt < 4; ++nt) {
        float s = zacc[nt];
        s += __shfl_xor(s, 16, 64);
        s += __shfl_xor(s, 32, 64);
        if (lane < 16) Zs[w * 64 + nt * 16 + lane] = s;
    }
    __syncthreads();

    // epilogue: Vt[bh][d][kb*256 + t] = bf16(V[k][d] / Z[k]); t <-> k-col
    {
        float rz = 1.0f / Zs[t];
        const float* vrow = v + ((size_t)(b * SKV) + kb * 256 + t) * DM + h * HD;
        size_t vtb = (size_t)bh * HD * SKV + kb * 256 + t;
#pragma unroll
        for (int dc = 0; dc < 4; ++dc) {
            float4 a0 = *(const float4*)(vrow + dc * 16 + 0);
            float4 a1 = *(const float4*)(vrow + dc * 16 + 4);
            float4 a2 = *(const float4*)(vrow + dc * 16 + 8);
            float4 a3 = *(const float4*)(vrow + dc * 16 + 12);
            float tmp[16] = {a0.x, a0.y, a0.z, a0.w, a1.x, a1.y, a1.z, a1.w,
                             a2.x, a2.y, a2.z, a2.w, a3.x, a3.y, a3.z, a3.w};
#pragma unroll
            for (int j = 0; j < 16; ++j)
                Vt[vtb + (size_t)(dc * 16 + j) * SKV] = (__bf16)(tmp[j] * rz);
        }
    }
}

// ---------------------------------------------------------------------------
// kattn: O[q,:] = sum_k exp(S[q,k]) * Vt[:,k]   (Vt pre-scaled by 1/Z)
// S^T formulation -> packed b64 E writes. grid (64 bh, 8 qb) for XCD affinity.
// ---------------------------------------------------------------------------
__global__ __launch_bounds__(256, 3) void kattn(const __bf16* __restrict__ Qh,
                                                const __bf16* __restrict__ Kh,
                                                const __bf16* __restrict__ Vt,
                                                __bf16* __restrict__ O) {
    const int bh = blockIdx.x;
    const int qb = blockIdx.y;
    const int b = bh >> 4, h = bh & 15;
    const int t = threadIdx.x;
    const int w = t >> 6, lane = t & 63;
    const int lo16 = lane & 15, quad = lane >> 4;
    const int wub = (t & 192) << 3;

    __shared__ __bf16 Ks[64 * 64];
    __shared__ __bf16 Vts[64 * 64];
    __shared__ __bf16 QE[256 * 64];   // Q staging, then per-wave E strips

    // async stage Q 256x64
    const __bf16* qgbase = Qh + ((size_t)bh * SQ + qb * 256) * HD;
#pragma unroll
    for (int i = 0; i < 8; ++i) {
        int ci = i * 256 + t;
        int row = ci >> 3;
        int c = (ci & 7) ^ (row & 7);
        ASYNC16(qgbase + row * 64 + c * 8, &QE[i * 2048 + wub]);
    }
    __syncthreads();

    // Q fragments (B-operand: n = q, kdim = d), persist in registers
    bf16x8 qf[4][2];
#pragma unroll
    for (int qt = 0; qt < 4; ++qt)
#pragma unroll
        for (int dh = 0; dh < 2; ++dh)
            qf[qt][dh] = *(const bf16x8*)(&QE[swz(w * 64 + qt * 16 + lo16, dh * 4 + quad)]);

    f32x4 oacc[4][4];
    f32x4 zero = {0.f, 0.f, 0.f, 0.f};
#pragma unroll
    for (int qt = 0; qt < 4; ++qt)
#pragma unroll
        for (int nt = 0; nt < 4; ++nt)
            oacc[qt][nt] = zero;

    __bf16* Ew = &QE[w * 64 * 64];
    const __bf16* kgbase = Kh + (size_t)bh * SKV * HD;
    const __bf16* vtgbase = Vt + (size_t)bh * HD * SKV;

    for (int kt = 0; kt < 32; ++kt) {
        __syncthreads();
        // async stage K tile 64x64 + Vt tile 64d x 64k
#pragma unroll
        for (int i = 0; i < 2; ++i) {
            int ci = i * 256 + t;
            int row = ci >> 3;
            int c = (ci & 7) ^ (row & 7);
            ASYNC16(kgbase + (size_t)kt * 64 * HD + row * 64 + c * 8, &Ks[i * 2048 + wub]);
            ASYNC16(vtgbase + (size_t)row * SKV + kt * 64 + c * 8, &Vts[i * 2048 + wub]);
        }
        __syncthreads();

        // S^T = K Q^T / 32; E = exp; packed b64 writes into wave-private strip
#pragma unroll
        for (int ktile = 0; ktile < 4; ++ktile) {
            bf16x8 ak0 = *(const bf16x8*)(&Ks[swz(ktile * 16 + lo16, quad)]);
            bf16x8 ak1 = *(const bf16x8*)(&Ks[swz(ktile * 16 + lo16, 4 + quad)]);
#pragma unroll
            for (int qt = 0; qt < 4; ++qt) {
                f32x4 s = zero;
                s = __builtin_amdgcn_mfma_f32_16x16x32_bf16(ak0, qf[qt][0], s, 0, 0, 0);
                s = __builtin_amdgcn_mfma_f32_16x16x32_bf16(ak1, qf[qt][1], s, 0, 0, 0);
                bf16x4 e;
                e[0] = (__bf16)EXPS(s[0]);
                e[1] = (__bf16)EXPS(s[1]);
                e[2] = (__bf16)EXPS(s[2]);
                e[3] = (__bf16)EXPS(s[3]);
                int er = qt * 16 + lo16;
                *(bf16x4*)(&Ew[(er << 6) + ((((2 * ktile + (quad >> 1))) ^ (er & 7)) << 3)
                               + (quad & 1) * 4]) = e;
            }
        }

        // O += E @ Vt^T   (intra-wave LDS round trip, no barrier)
#pragma unroll
        for (int kk2 = 0; kk2 < 2; ++kk2) {
            bf16x8 ae[4];
#pragma unroll
            for (int qt = 0; qt < 4; ++qt)
                ae[qt] = *(const bf16x8*)(&Ew[swz(qt * 16 + lo16, kk2 * 4 + quad)]);
#pragma unroll
            for (int nt = 0; nt < 4; ++nt) {
                bf16x8 bv = *(const bf16x8*)(&Vts[swz(nt * 16 + lo16, kk2 * 4 + quad)]);
#pragma unroll
                for (int qt = 0; qt < 4; ++qt)
                    oacc[qt][nt] = __builtin_amdgcn_mfma_f32_16x16x32_bf16(ae[qt], bv, oacc[qt][nt], 0, 0, 0);
            }
        }
    }

    size_t obase = ((size_t)(b * SQ) + qb * 256 + w * 64) * DM + h * HD;
#pragma unroll
    for (int qt = 0; qt < 4; ++qt)
#pragma unroll
        for (int nt = 0; nt < 4; ++nt)
#pragma unroll
            for (int r = 0; r < 4; ++r)
                O[obase + (size_t)(qt * 16 + quad * 4 + r) * DM + nt * 16 + lo16] =
                    (__bf16)oacc[qt][nt][r];
}

// ---------------------------------------------------------------------------
// kproj: out[n, i] = sum_j A[n,j] * W[i,j] + b[i]   (NT GEMM, 128x128 tiles)
// ---------------------------------------------------------------------------
__global__ __launch_bounds__(256, 3) void kproj(const __bf16* __restrict__ A,
                                                const __bf16* __restrict__ Wb,
                                                const float* __restrict__ bias,
                                                float* __restrict__ out) {
    const int nb = blockIdx.x;
    const int mb = blockIdx.y;
    const int t = threadIdx.x;
    const int w = t >> 6, lane = t & 63;
    const int lo16 = lane & 15, quad = lane >> 4;
    const int wm = w & 1, wn = w >> 1;
    const int wub = (t & 192) << 3;

    __shared__ __bf16 As[128 * 64];
    __shared__ __bf16 Bs[128 * 64];

    f32x4 acc[4][4];
    f32x4 zero = {0.f, 0.f, 0.f, 0.f};
#pragma unroll
    for (int mt = 0; mt < 4; ++mt)
#pragma unroll
        for (int nt = 0; nt < 4; ++nt)
            acc[mt][nt] = zero;

    const __bf16* abase = A + (size_t)(mb * 128) * DM;
    const __bf16* wbase = Wb + (size_t)(nb * 128) * DM;

    for (int kt = 0; kt < 16; ++kt) {
        __syncthreads();
#pragma unroll
        for (int i = 0; i < 4; ++i) {
            int ci = i * 256 + t;
            int row = ci >> 3;
            int c = (ci & 7) ^ (row & 7);
            ASYNC16(abase + (size_t)row * DM + kt * 64 + c * 8, &As[i * 2048 + wub]);
            ASYNC16(wbase + (size_t)row * DM + kt * 64 + c * 8, &Bs[i * 2048 + wub]);
        }
        __syncthreads();

#pragma unroll
        for (int ks = 0; ks < 2; ++ks) {
            bf16x8 av[4], bv[4];
#pragma unroll
            for (int mt = 0; mt < 4; ++mt)
                av[mt] = *(const bf16x8*)(&As[swz(wm * 64 + mt * 16 + lo16, ks * 4 + quad)]);
#pragma unroll
            for (int nt = 0; nt < 4; ++nt)
                bv[nt] = *(const bf16x8*)(&Bs[swz(wn * 64 + nt * 16 + lo16, ks * 4 + quad)]);
#pragma unroll
            for (int mt = 0; mt < 4; ++mt)
#pragma unroll
                for (int nt = 0; nt < 4; ++nt)
                    acc[mt][nt] = __builtin_amdgcn_mfma_f32_16x16x32_bf16(av[mt], bv[nt], acc[mt][nt], 0, 0, 0);
        }
    }

    const int col0 = nb * 128 + wn * 64;
    const int row0 = mb * 128 + wm * 64;
#pragma unroll
    for (int nt = 0; nt < 4; ++nt) {
        float bb = bias[col0 + nt * 16 + lo16];
#pragma unroll
        for (int mt = 0; mt < 4; ++mt)
#pragma unroll
            for (int r = 0; r < 4; ++r)
                out[(size_t)(row0 + mt * 16 + quad * 4 + r) * DM + col0 + nt * 16 + lo16] =
                    acc[mt][nt][r] + bb;
    }
}

// ---------------------------------------------------------------------------
extern "C" void kernel_launch(void* const* d_in, const int* in_sizes, int n_in,
                              void* d_out, int out_size, void* d_ws, size_t ws_size,
                              hipStream_t stream) {
    const float* q    = (const float*)d_in[0];
    const float* k    = (const float*)d_in[1];
    const float* v    = (const float*)d_in[2];
    const float* W    = (const float*)d_in[3];
    const float* bias = (const float*)d_in[4];
    float* out = (float*)d_out;

    char* ws = (char*)d_ws;
    __bf16* Qh = (__bf16*)ws;                          // 16 MB
    __bf16* Kh = (__bf16*)(ws + (16u << 20));          // 16 MB
    __bf16* Vt = (__bf16*)(ws + (32u << 20));          // 16 MB
    __bf16* Wb = (__bf16*)(ws + (48u << 20));          // 2 MB
    __bf16* O  = (__bf16*)(ws + (50u << 20));          // 16 MB

    kprep  <<<dim3(4096), 256, 0, stream>>>(q, Qh);
    kprep  <<<dim3(4096), 256, 0, stream>>>(k, Kh);
    kconv_w<<<dim3(1024), 256, 0, stream>>>(W, Wb);
    kz     <<<dim3(64, 8), 256, 0, stream>>>(Qh, Kh, v, Vt);
    kattn  <<<dim3(64, 8), 256, 0, stream>>>(Qh, Kh, Vt, O);
    kproj  <<<dim3(8, 64), 256, 0, stream>>>(O, Wb, bias, out);
}

// Round 4
// 294.409 us; speedup vs baseline: 1.2740x; 1.0139x over previous
//
#include <hip/hip_runtime.h>

#define NH    16
#define HD    64
#define SQ    2048
#define SKV   2048
#define DM    1024

typedef __attribute__((ext_vector_type(8))) __bf16 bf16x8;
typedef __attribute__((ext_vector_type(4))) __bf16 bf16x4;
typedef __attribute__((ext_vector_type(4))) float  f32x4;

// async global->LDS, 16B per lane; LDS dest = wave-uniform base + lane*16
#define ASYNC16(gp, lp)                                                        \
    __builtin_amdgcn_global_load_lds(                                          \
        (const __attribute__((address_space(1))) void*)(gp),                   \
        (__attribute__((address_space(3))) void*)(lp), 16, 0, 0)

// exp(x/32) = exp2(x * log2(e)/32): single v_mul + v_exp_f32
#if __has_builtin(__builtin_amdgcn_exp2f)
#define EXPS(x) __builtin_amdgcn_exp2f((x) * 0.04508422f)
#else
#define EXPS(x) __expf((x) * 0.03125f)
#endif

// swizzled LDS tile: 64 elems/row, 8 chunks of 8 bf16; chunk' = chunk ^ (row&7)
static __device__ __forceinline__ int swz(int row, int chunk) {
    return (row << 6) + (((chunk) ^ (row & 7)) << 3);
}

static __device__ __forceinline__ bf16x4 cvt4(float4 v) {
    bf16x4 r;
    r[0] = (__bf16)v.x; r[1] = (__bf16)v.y; r[2] = (__bf16)v.z; r[3] = (__bf16)v.w;
    return r;
}

// ---------------------------------------------------------------------------
// kprep_all: one launch for Q-prep, K-prep, W-convert.
//   bid < 4096: Q [b][s][h*64+d] fp32 -> [bh][s][d] bf16
//   bid < 8192: K same
//   else      : W fp32 -> bf16
// ---------------------------------------------------------------------------
__global__ void kprep_all(const float* __restrict__ q, const float* __restrict__ k,
                          const float* __restrict__ W,
                          __bf16* __restrict__ Qh, __bf16* __restrict__ Kh,
                          __bf16* __restrict__ Wb) {
    int bid = blockIdx.x;
    if (bid < 8192) {
        const float* src = (bid < 4096) ? q : k;
        __bf16* dst = (bid < 4096) ? Qh : Kh;
        size_t g = (size_t)(bid & 4095) * 256 + threadIdx.x;
        size_t o = g * 8;
        int c  = (int)(o & 63);
        int s  = (int)((o >> 6) & 2047);
        int bh = (int)(o >> 17);
        int b = bh >> 4, h = bh & 15;
        const float* p = src + ((size_t)(b * SQ + s)) * DM + h * HD + c;
        float4 v0 = *(const float4*)p;
        float4 v1 = *(const float4*)(p + 4);
        bf16x8 r;
        r[0] = (__bf16)v0.x; r[1] = (__bf16)v0.y; r[2] = (__bf16)v0.z; r[3] = (__bf16)v0.w;
        r[4] = (__bf16)v1.x; r[5] = (__bf16)v1.y; r[6] = (__bf16)v1.z; r[7] = (__bf16)v1.w;
        *(bf16x8*)(dst + o) = r;
    } else {
        int i = (bid - 8192) * 256 + threadIdx.x;
        float4 v = *(const float4*)(W + (size_t)i * 4);
        *(bf16x4*)(Wb + (size_t)i * 4) = cvt4(v);
    }
}

// ---------------------------------------------------------------------------
// kz: Z[k] = sum_q exp(QK^T/32); epilogue writes Vt[bh][d][k] = bf16(V/Z)
// grid (64 bh, 8 kb): XCD affinity on bh. Q tiles double-buffered.
// ---------------------------------------------------------------------------
__global__ __launch_bounds__(256, 2) void kz(const __bf16* __restrict__ Qh,
                                             const __bf16* __restrict__ Kh,
                                             const float* __restrict__ v,
                                             __bf16* __restrict__ Vt) {
    const int bh = blockIdx.x;
    const int kb = blockIdx.y;
    const int b = bh >> 4, h = bh & 15;
    const int t = threadIdx.x;
    const int w = t >> 6, lane = t & 63;
    const int lo16 = lane & 15, quad = lane >> 4;
    const int wub = (t & 192) << 3;          // wave-uniform chunk base (elems)

    __shared__ __bf16 Ks[256 * 64];
    __shared__ __bf16 Qs[2][64 * 64];
    __shared__ float  Zs[256];

    const __bf16* kbase = Kh + ((size_t)bh * SKV + kb * 256) * HD;
    const __bf16* qbase = Qh + (size_t)bh * SQ * HD;

    // stage K 256x64 + Q tile 0 (async, swizzle folded into global offsets)
#pragma unroll
    for (int i = 0; i < 8; ++i) {
        int ci = i * 256 + t;
        int row = ci >> 3;
        int c = (ci & 7) ^ (row & 7);
        ASYNC16(kbase + row * 64 + c * 8, &Ks[i * 2048 + wub]);
    }
#pragma unroll
    for (int i = 0; i < 2; ++i) {
        int ci = i * 256 + t;
        int row = ci >> 3;
        int c = (ci & 7) ^ (row & 7);
        ASYNC16(qbase + row * 64 + c * 8, &Qs[0][i * 2048 + wub]);
    }
    __syncthreads();

    // hoist K fragments (B-operand: n = k-col, kdim = d)
    bf16x8 bk[4][2];
#pragma unroll
    for (int nt = 0; nt < 4; ++nt)
#pragma unroll
        for (int dh = 0; dh < 2; ++dh)
            bk[nt][dh] = *(const bf16x8*)(&Ks[swz(w * 64 + nt * 16 + lo16, dh * 4 + quad)]);

    float zacc[4] = {0.f, 0.f, 0.f, 0.f};

    for (int qt = 0; qt < 32; ++qt) {
        const int cur = qt & 1, nxt = cur ^ 1;
        if (qt < 31) {
#pragma unroll
            for (int i = 0; i < 2; ++i) {
                int ci = i * 256 + t;
                int row = ci >> 3;
                int c = (ci & 7) ^ (row & 7);
                ASYNC16(qbase + (size_t)(qt + 1) * 64 * HD + row * 64 + c * 8,
                        &Qs[nxt][i * 2048 + wub]);
            }
        }

#pragma unroll
        for (int mt = 0; mt < 4; ++mt) {
            bf16x8 aq0 = *(const bf16x8*)(&Qs[cur][swz(mt * 16 + lo16, quad)]);
            bf16x8 aq1 = *(const bf16x8*)(&Qs[cur][swz(mt * 16 + lo16, 4 + quad)]);
#pragma unroll
            for (int nt = 0; nt < 4; ++nt) {
                f32x4 acc = {0.f, 0.f, 0.f, 0.f};
                acc = __builtin_amdgcn_mfma_f32_16x16x32_bf16(aq0, bk[nt][0], acc, 0, 0, 0);
                acc = __builtin_amdgcn_mfma_f32_16x16x32_bf16(aq1, bk[nt][1], acc, 0, 0, 0);
                zacc[nt] += EXPS(acc[0]) + EXPS(acc[1]) + EXPS(acc[2]) + EXPS(acc[3]);
            }
        }
        __syncthreads();
    }

#pragma unroll
    for (int nt = 0; nt < 4; ++nt) {
        float s = zacc[nt];
        s += __shfl_xor(s, 16, 64);
        s += __shfl_xor(s, 32, 64);
        if (lane < 16) Zs[w * 64 + nt * 16 + lane] = s;
    }
    __syncthreads();

    // epilogue: Vt[bh][d][kb*256 + t] = bf16(V[k][d] / Z[k]); t <-> k-col
    {
        float rz = 1.0f / Zs[t];
        const float* vrow = v + ((size_t)(b * SKV) + kb * 256 + t) * DM + h * HD;
        size_t vtb = (size_t)bh * HD * SKV + kb * 256 + t;
#pragma unroll
        for (int dc = 0; dc < 4; ++dc) {
            float4 a0 = *(const float4*)(vrow + dc * 16 + 0);
            float4 a1 = *(const float4*)(vrow + dc * 16 + 4);
            float4 a2 = *(const float4*)(vrow + dc * 16 + 8);
            float4 a3 = *(const float4*)(vrow + dc * 16 + 12);
            float tmp[16] = {a0.x, a0.y, a0.z, a0.w, a1.x, a1.y, a1.z, a1.w,
                             a2.x, a2.y, a2.z, a2.w, a3.x, a3.y, a3.z, a3.w};
#pragma unroll
            for (int j = 0; j < 16; ++j)
                Vt[vtb + (size_t)(dc * 16 + j) * SKV] = (__bf16)(tmp[j] * rz);
        }
    }
}

// ---------------------------------------------------------------------------
// kattn: O[q,:] = sum_k exp(S[q,k]) * Vt[:,k]   (Vt pre-scaled by 1/Z)
// S^T formulation; K/Vt tiles double-buffered; one barrier per k-tile.
// grid (64 bh, 8 qb) for XCD affinity.
// ---------------------------------------------------------------------------
__global__ __launch_bounds__(256, 2) void kattn(const __bf16* __restrict__ Qh,
                                                const __bf16* __restrict__ Kh,
                                                const __bf16* __restrict__ Vt,
                                                __bf16* __restrict__ O) {
    const int bh = blockIdx.x;
    const int qb = blockIdx.y;
    const int b = bh >> 4, h = bh & 15;
    const int t = threadIdx.x;
    const int w = t >> 6, lane = t & 63;
    const int lo16 = lane & 15, quad = lane >> 4;
    const int wub = (t & 192) << 3;

    __shared__ __bf16 Ks[2][64 * 64];
    __shared__ __bf16 Vts[2][64 * 64];
    __shared__ __bf16 QE[256 * 64];   // Q staging, then per-wave E strips

    const __bf16* qgbase = Qh + ((size_t)bh * SQ + qb * 256) * HD;
    const __bf16* kgbase = Kh + (size_t)bh * SKV * HD;
    const __bf16* vtgbase = Vt + (size_t)bh * HD * SKV;

    // stage Q 256x64 + K/Vt tile 0
#pragma unroll
    for (int i = 0; i < 8; ++i) {
        int ci = i * 256 + t;
        int row = ci >> 3;
        int c = (ci & 7) ^ (row & 7);
        ASYNC16(qgbase + row * 64 + c * 8, &QE[i * 2048 + wub]);
    }
#pragma unroll
    for (int i = 0; i < 2; ++i) {
        int ci = i * 256 + t;
        int row = ci >> 3;
        int c = (ci & 7) ^ (row & 7);
        ASYNC16(kgbase + row * 64 + c * 8, &Ks[0][i * 2048 + wub]);
        ASYNC16(vtgbase + (size_t)row * SKV + c * 8, &Vts[0][i * 2048 + wub]);
    }
    __syncthreads();

    // Q fragments (B-operand: n = q, kdim = d), persist in registers
    bf16x8 qf[4][2];
#pragma unroll
    for (int qt = 0; qt < 4; ++qt)
#pragma unroll
        for (int dh = 0; dh < 2; ++dh)
            qf[qt][dh] = *(const bf16x8*)(&QE[swz(w * 64 + qt * 16 + lo16, dh * 4 + quad)]);

    f32x4 oacc[4][4];
    f32x4 zero = {0.f, 0.f, 0.f, 0.f};
#pragma unroll
    for (int qt = 0; qt < 4; ++qt)
#pragma unroll
        for (int nt = 0; nt < 4; ++nt)
            oacc[qt][nt] = zero;

    __bf16* Ew = &QE[w * 64 * 64];

    for (int kt = 0; kt < 32; ++kt) {
        const int cur = kt & 1, nxt = cur ^ 1;
        if (kt < 31) {
#pragma unroll
            for (int i = 0; i < 2; ++i) {
                int ci = i * 256 + t;
                int row = ci >> 3;
                int c = (ci & 7) ^ (row & 7);
                ASYNC16(kgbase + (size_t)(kt + 1) * 64 * HD + row * 64 + c * 8,
                        &Ks[nxt][i * 2048 + wub]);
                ASYNC16(vtgbase + (size_t)row * SKV + (kt + 1) * 64 + c * 8,
                        &Vts[nxt][i * 2048 + wub]);
            }
        }

        // S^T = K Q^T / 32; E = exp; packed b64 writes into wave-private strip
#pragma unroll
        for (int ktile = 0; ktile < 4; ++ktile) {
            bf16x8 ak0 = *(const bf16x8*)(&Ks[cur][swz(ktile * 16 + lo16, quad)]);
            bf16x8 ak1 = *(const bf16x8*)(&Ks[cur][swz(ktile * 16 + lo16, 4 + quad)]);
#pragma unroll
            for (int qt = 0; qt < 4; ++qt) {
                f32x4 s = zero;
                s = __builtin_amdgcn_mfma_f32_16x16x32_bf16(ak0, qf[qt][0], s, 0, 0, 0);
                s = __builtin_amdgcn_mfma_f32_16x16x32_bf16(ak1, qf[qt][1], s, 0, 0, 0);
                bf16x4 e;
                e[0] = (__bf16)EXPS(s[0]);
                e[1] = (__bf16)EXPS(s[1]);
                e[2] = (__bf16)EXPS(s[2]);
                e[3] = (__bf16)EXPS(s[3]);
                int er = qt * 16 + lo16;
                *(bf16x4*)(&Ew[(er << 6) + ((((2 * ktile + (quad >> 1))) ^ (er & 7)) << 3)
                               + (quad & 1) * 4]) = e;
            }
        }

        // O += E @ Vt^T   (intra-wave LDS round trip, no barrier)
#pragma unroll
        for (int kk2 = 0; kk2 < 2; ++kk2) {
            bf16x8 ae[4];
#pragma unroll
            for (int qt = 0; qt < 4; ++qt)
                ae[qt] = *(const bf16x8*)(&Ew[swz(qt * 16 + lo16, kk2 * 4 + quad)]);
#pragma unroll
            for (int nt = 0; nt < 4; ++nt) {
                bf16x8 bv = *(const bf16x8*)(&Vts[cur][swz(nt * 16 + lo16, kk2 * 4 + quad)]);
#pragma unroll
                for (int qt = 0; qt < 4; ++qt)
                    oacc[qt][nt] = __builtin_amdgcn_mfma_f32_16x16x32_bf16(ae[qt], bv, oacc[qt][nt], 0, 0, 0);
            }
        }
        __syncthreads();
    }

    size_t obase = ((size_t)(b * SQ) + qb * 256 + w * 64) * DM + h * HD;
#pragma unroll
    for (int qt = 0; qt < 4; ++qt)
#pragma unroll
        for (int nt = 0; nt < 4; ++nt)
#pragma unroll
            for (int r = 0; r < 4; ++r)
                O[obase + (size_t)(qt * 16 + quad * 4 + r) * DM + nt * 16 + lo16] =
                    (__bf16)oacc[qt][nt][r];
}

// ---------------------------------------------------------------------------
// kproj: out[n, i] = sum_j A[n,j] * W[i,j] + b[i]   (NT GEMM, 128x128 tiles,
// double-buffered)
// ---------------------------------------------------------------------------
__global__ __launch_bounds__(256, 2) void kproj(const __bf16* __restrict__ A,
                                                const __bf16* __restrict__ Wb,
                                                const float* __restrict__ bias,
                                                float* __restrict__ out) {
    const int nb = blockIdx.x;
    const int mb = blockIdx.y;
    const int t = threadIdx.x;
    const int w = t >> 6, lane = t & 63;
    const int lo16 = lane & 15, quad = lane >> 4;
    const int wm = w & 1, wn = w >> 1;
    const int wub = (t & 192) << 3;

    __shared__ __bf16 As[2][128 * 64];
    __shared__ __bf16 Bs[2][128 * 64];

    f32x4 acc[4][4];
    f32x4 zero = {0.f, 0.f, 0.f, 0.f};
#pragma unroll
    for (int mt = 0; mt < 4; ++mt)
#pragma unroll
        for (int nt = 0; nt < 4; ++nt)
            acc[mt][nt] = zero;

    const __bf16* abase = A + (size_t)(mb * 128) * DM;
    const __bf16* wbase = Wb + (size_t)(nb * 128) * DM;

#pragma unroll
    for (int i = 0; i < 4; ++i) {
        int ci = i * 256 + t;
        int row = ci >> 3;
        int c = (ci & 7) ^ (row & 7);
        ASYNC16(abase + (size_t)row * DM + c * 8, &As[0][i * 2048 + wub]);
        ASYNC16(wbase + (size_t)row * DM + c * 8, &Bs[0][i * 2048 + wub]);
    }
    __syncthreads();

    for (int kt = 0; kt < 16; ++kt) {
        const int cur = kt & 1, nxt = cur ^ 1;
        if (kt < 15) {
#pragma unroll
            for (int i = 0; i < 4; ++i) {
                int ci = i * 256 + t;
                int row = ci >> 3;
                int c = (ci & 7) ^ (row & 7);
                ASYNC16(abase + (size_t)row * DM + (kt + 1) * 64 + c * 8, &As[nxt][i * 2048 + wub]);
                ASYNC16(wbase + (size_t)row * DM + (kt + 1) * 64 + c * 8, &Bs[nxt][i * 2048 + wub]);
            }
        }

#pragma unroll
        for (int ks = 0; ks < 2; ++ks) {
            bf16x8 av[4], bv[4];
#pragma unroll
            for (int mt = 0; mt < 4; ++mt)
                av[mt] = *(const bf16x8*)(&As[cur][swz(wm * 64 + mt * 16 + lo16, ks * 4 + quad)]);
#pragma unroll
            for (int nt = 0; nt < 4; ++nt)
                bv[nt] = *(const bf16x8*)(&Bs[cur][swz(wn * 64 + nt * 16 + lo16, ks * 4 + quad)]);
#pragma unroll
            for (int mt = 0; mt < 4; ++mt)
#pragma unroll
                for (int nt = 0; nt < 4; ++nt)
                    acc[mt][nt] = __builtin_amdgcn_mfma_f32_16x16x32_bf16(av[mt], bv[nt], acc[mt][nt], 0, 0, 0);
        }
        __syncthreads();
    }

    const int col0 = nb * 128 + wn * 64;
    const int row0 = mb * 128 + wm * 64;
#pragma unroll
    for (int nt = 0; nt < 4; ++nt) {
        float bb = bias[col0 + nt * 16 + lo16];
#pragma unroll
        for (int mt = 0; mt < 4; ++mt)
#pragma unroll
            for (int r = 0; r < 4; ++r)
                out[(size_t)(row0 + mt * 16 + quad * 4 + r) * DM + col0 + nt * 16 + lo16] =
                    acc[mt][nt][r] + bb;
    }
}

// ---------------------------------------------------------------------------
extern "C" void kernel_launch(void* const* d_in, const int* in_sizes, int n_in,
                              void* d_out, int out_size, void* d_ws, size_t ws_size,
                              hipStream_t stream) {
    const float* q    = (const float*)d_in[0];
    const float* k    = (const float*)d_in[1];
    const float* v    = (const float*)d_in[2];
    const float* W    = (const float*)d_in[3];
    const float* bias = (const float*)d_in[4];
    float* out = (float*)d_out;

    char* ws = (char*)d_ws;
    __bf16* Qh = (__bf16*)ws;                          // 16 MB
    __bf16* Kh = (__bf16*)(ws + (16u << 20));          // 16 MB
    __bf16* Vt = (__bf16*)(ws + (32u << 20));          // 16 MB
    __bf16* Wb = (__bf16*)(ws + (48u << 20));          // 2 MB
    __bf16* O  = (__bf16*)(ws + (50u << 20));          // 16 MB

    kprep_all<<<dim3(9216), 256, 0, stream>>>(q, k, W, Qh, Kh, Wb);
    kz       <<<dim3(64, 8), 256, 0, stream>>>(Qh, Kh, v, Vt);
    kattn    <<<dim3(64, 8), 256, 0, stream>>>(Qh, Kh, Vt, O);
    kproj    <<<dim3(8, 64), 256, 0, stream>>>(O, Wb, bias, out);
}